// Round 1
// baseline (116.626 us; speedup 1.0000x reference)
//
#include <hip/hip_runtime.h>
#include <hip/hip_bf16.h>

#define L_N 64
#define T_N 8192
#define K_N 128
#define N_N 128
#define BM  128

typedef __attribute__((ext_vector_type(8))) short short8;   // 8 bf16 = 4 VGPR
typedef __attribute__((ext_vector_type(4))) float f32x4;    // MFMA acc

__device__ __forceinline__ unsigned short f2bf(float f) {
    union { float f; unsigned u; } c; c.f = f;
    return (unsigned short)((c.u + 0x7fffu + ((c.u >> 16) & 1u)) >> 16);  // RNE
}

// Prepass: w [L][K][N] fp32 -> wT [L][N][K] bf16 (so B-fragments are K-contiguous)
__global__ __launch_bounds__(256) void wT_kernel(const float* __restrict__ w,
                                                 unsigned short* __restrict__ wT) {
    __shared__ float lds[128 * 129];   // +1 pad: conflict-free column reads
    const int l = blockIdx.x;
    const float* wl = w + (size_t)l * (K_N * N_N);
    const int tid = threadIdx.x;
    #pragma unroll 4
    for (int i = 0; i < 64; ++i) {
        int idx = i * 256 + tid;            // flat = k*128 + n (coalesced)
        int k = idx >> 7, n = idx & 127;
        lds[k * 129 + n] = wl[idx];
    }
    __syncthreads();
    unsigned short* o = wT + (size_t)l * (K_N * N_N);
    #pragma unroll 4
    for (int i = 0; i < 64; ++i) {
        int idx = i * 256 + tid;            // flat = n*128 + k (coalesced write)
        int n = idx >> 7, k = idx & 127;
        o[idx] = f2bf(lds[k * 129 + n]);
    }
}

// Main: one block = one (layer, 128-row tile). K=128 in one LDS tile, single barrier.
__global__ __launch_bounds__(256) void gl_kernel(const float* __restrict__ x,
                                                 const unsigned short* __restrict__ wT,
                                                 const float* __restrict__ bias,
                                                 float* __restrict__ out) {
    __shared__ unsigned short xs [BM  * K_N];   // 32 KB, XOR-swizzled
    __shared__ unsigned short wsh[N_N * K_N];   // 32 KB, XOR-swizzled ([n][k] = w^T)

    const int tid = threadIdx.x;
    const int l  = blockIdx.x >> 6;             // T_N/BM = 64 tiles/layer
    const int t0 = (blockIdx.x & 63) * BM;
    const float* xg = x + ((size_t)l * T_N + t0) * K_N;

    // stage x tile: 128x128 fp32 -> bf16, swizzle (row&7)<<3 (ushort units = 16B byte-swz)
    #pragma unroll
    for (int i = 0; i < 16; ++i) {
        int f = i * 256 + tid;                  // float4 index; coalesced 16B/lane
        const float4 v = ((const float4*)xg)[f];
        int row = f >> 5;
        int kc  = (f & 31) * 4;
        union { unsigned short s[4]; unsigned long long u; } p;
        p.s[0] = f2bf(v.x); p.s[1] = f2bf(v.y); p.s[2] = f2bf(v.z); p.s[3] = f2bf(v.w);
        int us = (row * K_N + kc) ^ ((row & 7) << 3);
        *(unsigned long long*)&xs[us] = p.u;
    }
    // stage wT tile: 128x128 bf16, 16B/lane
    const unsigned short* wg = wT + (size_t)l * (K_N * N_N);
    #pragma unroll
    for (int i = 0; i < 8; ++i) {
        int c = i * 256 + tid;                  // 16B chunk index
        short8 v = ((const short8*)wg)[c];
        int row = c >> 4;
        int us = (c * 8) ^ ((row & 7) << 3);
        *(short8*)&wsh[us] = v;
    }
    __syncthreads();

    const int wid  = tid >> 6;                  // 4 waves: 2x2, each 64x64 out
    const int lane = tid & 63;
    const int wm = wid >> 1, wn = wid & 1;
    const int lr = lane & 15;                   // A-row / B-col within fragment
    const int lg = lane >> 4;                   // k-group

    f32x4 acc[4][4];
    #pragma unroll
    for (int mi = 0; mi < 4; ++mi)
        #pragma unroll
        for (int ni = 0; ni < 4; ++ni)
            acc[mi][ni] = (f32x4){0.f, 0.f, 0.f, 0.f};

    #pragma unroll
    for (int kk = 0; kk < 4; ++kk) {
        const int kbase = kk * 32 + lg * 8;
        short8 a[4], bq[4];
        #pragma unroll
        for (int mi = 0; mi < 4; ++mi) {
            int row = wm * 64 + mi * 16 + lr;
            a[mi] = *(const short8*)&xs[(row * K_N + kbase) ^ ((row & 7) << 3)];
        }
        #pragma unroll
        for (int ni = 0; ni < 4; ++ni) {
            int row = wn * 64 + ni * 16 + lr;
            bq[ni] = *(const short8*)&wsh[(row * K_N + kbase) ^ ((row & 7) << 3)];
        }
        #pragma unroll
        for (int mi = 0; mi < 4; ++mi)
            #pragma unroll
            for (int ni = 0; ni < 4; ++ni)
                acc[mi][ni] = __builtin_amdgcn_mfma_f32_16x16x32_bf16(
                                  a[mi], bq[ni], acc[mi][ni], 0, 0, 0);
    }

    float bv[4];
    #pragma unroll
    for (int ni = 0; ni < 4; ++ni)
        bv[ni] = bias[l * N_N + wn * 64 + ni * 16 + lr];

    float* og = out + ((size_t)l * T_N + t0) * N_N;
    #pragma unroll
    for (int mi = 0; mi < 4; ++mi) {
        #pragma unroll
        for (int ni = 0; ni < 4; ++ni) {
            const int col   = wn * 64 + ni * 16 + lr;
            const int rbase = wm * 64 + mi * 16 + lg * 4;
            #pragma unroll
            for (int j = 0; j < 4; ++j)
                og[(size_t)(rbase + j) * N_N + col] = acc[mi][ni][j] + bv[ni];
        }
    }
}

extern "C" void kernel_launch(void* const* d_in, const int* in_sizes, int n_in,
                              void* d_out, int out_size, void* d_ws, size_t ws_size,
                              hipStream_t stream) {
    const float* x = (const float*)d_in[0];
    const float* w = (const float*)d_in[1];
    const float* b = (const float*)d_in[2];
    float* out = (float*)d_out;
    unsigned short* wT = (unsigned short*)d_ws;   // 2 MB scratch, rewritten every call

    wT_kernel<<<L_N, 256, 0, stream>>>(w, wT);
    gl_kernel<<<L_N * (T_N / BM), 256, 0, stream>>>(x, wT, b, out);
}